// Round 4
// baseline (377.453 us; speedup 1.0000x reference)
//
#include <hip/hip_runtime.h>
#include <hip/hip_fp16.h>

#define NN 8192
#define INF 256
#define OUTF 128
#define LOG2E 1.44269504088896340736f

typedef float f32x4 __attribute__((ext_vector_type(4)));
typedef float f32x16 __attribute__((ext_vector_type(16)));
typedef __fp16 h16x8 __attribute__((ext_vector_type(8)));
typedef __fp16 h16x4 __attribute__((ext_vector_type(4)));
typedef __fp16 h16x2 __attribute__((ext_vector_type(2)));
typedef int i32x4 __attribute__((ext_vector_type(4)));

// ---------------- K0: W (256x128 f32) -> WT_perm f16 (for K1's 32x32x16 MFMA)
__global__ __launch_bounds__(256) void k0_wt(const float* __restrict__ W1,
                                             const float* __restrict__ W2,
                                             __fp16* __restrict__ WT) {
  int m = blockIdx.x * 256 + threadIdx.x;  // 8192 chunks of 16B
  int h = m >> 12;
  int r = m & 4095;
  int c = r >> 5;
  int kb = (r >> 1) & 15;
  int hh = r & 1;
  const float* W = h ? W2 : W1;
  float v[8];
#pragma unroll
  for (int s = 0; s < 8; ++s) {
    int koff = 4 * hh + (s & 3) + 8 * (s >> 2);
    v[s] = W[(kb * 16 + koff) * OUTF + c];
  }
  union { h16x2 h2[4]; i32x4 q; } u;
  u.h2[0] = __builtin_amdgcn_cvt_pkrtz(v[0], v[1]);
  u.h2[1] = __builtin_amdgcn_cvt_pkrtz(v[2], v[3]);
  u.h2[2] = __builtin_amdgcn_cvt_pkrtz(v[4], v[5]);
  u.h2[3] = __builtin_amdgcn_cvt_pkrtz(v[6], v[7]);
  *(i32x4*)(WT + (size_t)h * 32768 + c * 256 + kb * 16 + hh * 8) = u.q;
}

// ---------------- K1: h = inp@W via MFMA; emits hT_perm16 (16x16x32 B-frag layout),
// src' and dst' scaled by log2e
__global__ __launch_bounds__(128) void k1_h(
    const float* __restrict__ inp, const __fp16* __restrict__ WT,
    const float* __restrict__ a1, const float* __restrict__ a2,
    __fp16* __restrict__ hT, float* __restrict__ S, float* __restrict__ D) {
  __shared__ __align__(16) float hl[2][32][136];
  int tid = threadIdx.x;
  int w = tid >> 6;           // wave = head
  int l = tid & 63;
  int lr = l & 31, g = l >> 5;
  int i0 = blockIdx.x * 32;
  const __fp16* WTh = WT + (size_t)w * 32768;
  f32x16 acc[4];
#pragma unroll
  for (int nf = 0; nf < 4; ++nf)
#pragma unroll
    for (int e = 0; e < 16; ++e) acc[nf][e] = 0.0f;
  const float* ip = inp + (size_t)(i0 + lr) * INF;
#pragma unroll
  for (int kb = 0; kb < 16; ++kb) {
    f32x4 q0 = *(const f32x4*)(ip + kb * 16 + 4 * g);
    f32x4 q1 = *(const f32x4*)(ip + kb * 16 + 8 + 4 * g);
    union { h16x2 h2[4]; h16x8 h8; } ua;
    ua.h2[0] = __builtin_amdgcn_cvt_pkrtz(q0[0], q0[1]);
    ua.h2[1] = __builtin_amdgcn_cvt_pkrtz(q0[2], q0[3]);
    ua.h2[2] = __builtin_amdgcn_cvt_pkrtz(q1[0], q1[1]);
    ua.h2[3] = __builtin_amdgcn_cvt_pkrtz(q1[2], q1[3]);
#pragma unroll
    for (int nf = 0; nf < 4; ++nf) {
      h16x8 b = *(const h16x8*)(WTh + (nf * 32 + lr) * 256 + kb * 16 + g * 8);
      acc[nf] = __builtin_amdgcn_mfma_f32_32x32x16_f16(ua.h8, b, acc[nf], 0, 0, 0);
    }
  }
#pragma unroll
  for (int nf = 0; nf < 4; ++nf)
#pragma unroll
    for (int r = 0; r < 16; ++r) {
      int row = (r & 3) + 8 * (r >> 2) + 4 * g;
      hl[w][row][nf * 32 + lr] = acc[nf][r];
    }
  __syncthreads();
  const float* av = w ? a2 : a1;
  float s = 0.f, d = 0.f;
#pragma unroll
  for (int cc = 0; cc < 64; cc += 4) {
    int c = g * 64 + cc;
    f32x4 hv = *(const f32x4*)&hl[w][lr][c];
    f32x4 as = *(const f32x4*)(av + c);
    f32x4 ad = *(const f32x4*)(av + 128 + c);
    s += hv[0] * as[0] + hv[1] * as[1] + hv[2] * as[2] + hv[3] * as[3];
    d += hv[0] * ad[0] + hv[1] * ad[1] + hv[2] * ad[2] + hv[3] * ad[3];
  }
  s += __shfl_xor(s, 32);
  d += __shfl_xor(d, 32);
  if (g == 0) {
    S[(size_t)w * NN + i0 + lr] = s * LOG2E;
    D[(size_t)w * NN + i0 + lr] = d * LOG2E;
  }
  // hT_perm16: [head][jb32][col128][g4][8slots] f16; jb32 = blockIdx.x (rows i0..i0+31)
  __fp16* hTh = hT + (size_t)w * (NN * OUTF) + (size_t)blockIdx.x * 4096;
#pragma unroll
  for (int it = 0; it < 8; ++it) {
    int m = it * 64 + l;            // 512 16B-chunks
    int col = m & 127, gw = m >> 7; // gw = k-group 0..3
    float v[8];
#pragma unroll
    for (int s2 = 0; s2 < 8; ++s2) v[s2] = hl[w][gw * 8 + s2][col];
    union { h16x2 h2[4]; i32x4 q; } u2;
    u2.h2[0] = __builtin_amdgcn_cvt_pkrtz(v[0], v[1]);
    u2.h2[1] = __builtin_amdgcn_cvt_pkrtz(v[2], v[3]);
    u2.h2[2] = __builtin_amdgcn_cvt_pkrtz(v[4], v[5]);
    u2.h2[3] = __builtin_amdgcn_cvt_pkrtz(v[6], v[7]);
    *(i32x4*)(hTh + col * 32 + gw * 8) = u2.q;
  }
}

// ---------------- K1c: gmax' per head
__global__ __launch_bounds__(256) void k1c_gmax(const float* __restrict__ D,
                                                float* __restrict__ GM) {
  __shared__ float r1[256], r2[256];
  int t = threadIdx.x;
  float m1 = -1e30f, m2 = -1e30f;
  for (int i = t; i < NN; i += 256) {
    m1 = fmaxf(m1, D[i]);
    m2 = fmaxf(m2, D[NN + i]);
  }
  r1[t] = m1; r2[t] = m2;
  __syncthreads();
  for (int s = 128; s > 0; s >>= 1) {
    if (t < s) { r1[t] = fmaxf(r1[t], r1[t + s]); r2[t] = fmaxf(r2[t], r2[t + s]); }
    __syncthreads();
  }
  if (t == 0) { GM[0] = r1[0]; GM[1] = r2[0]; }
}

// ---------------- K2: fully fused adj-stream + mask + softmax + PV. No LDS.
// grid 2048 = 256 rowblocks(BM=32) x 8 js; 4 waves = 2 heads x 2 rowgroups of 16.
__global__ __launch_bounds__(256, 6) void k2_attn(
    const int* __restrict__ adj, const __fp16* __restrict__ hT,
    const float* __restrict__ S, const float* __restrict__ D,
    const float* __restrict__ GM, __fp16* __restrict__ NUM, float* __restrict__ DEN) {
  int tid = threadIdx.x;
  int w = tid >> 6;
  int l = tid & 63;
  int c16 = l & 15, g4 = l >> 4;
  int h = w >> 1, rg = w & 1;
  int rb = blockIdx.x >> 3, js = blockIdx.x & 7;
  int i0 = rb * 32;
  int row = i0 + rg * 16 + c16;
  float sf = S[(size_t)h * NN + row];
  float gm = GM[h];
  float v0 = sf + gm;
  float cneg = -fmaxf(v0, 0.2f * v0) - 1000.0f;  // arg = LRelu' + cneg + adj*1000
  const __fp16* hTh = hT + (size_t)h * (NN * OUTF) + (size_t)(js * 32) * 4096 +
                      c16 * 32 + g4 * 8;
  const float* Dh = D + (size_t)h * NN + js * 1024 + g4 * 8;
  const int* arow = adj + (size_t)row * NN + js * 1024 + g4 * 8;

  f32x4 acc[8];
#pragma unroll
  for (int nf = 0; nf < 8; ++nf) acc[nf] = {0.f, 0.f, 0.f, 0.f};
  float dsum = 0.f;

  // register prefetch, 1 ks-step deep (adj + dst')
  i32x4 ca0 = *(const i32x4*)(arow);
  i32x4 ca1 = *(const i32x4*)(arow + 4);
  f32x4 cd0 = *(const f32x4*)(Dh);
  f32x4 cd1 = *(const f32x4*)(Dh + 4);

#pragma unroll 2
  for (int ks = 0; ks < 32; ++ks) {
    float pv[8];
#pragma unroll
    for (int s = 0; s < 8; ++s) {
      float dd = (s < 4) ? cd0[s] : cd1[s - 4];
      int aa = (s < 4) ? ca0[s] : ca1[s - 4];
      float tt = sf + dd;
      float u = fmaxf(tt, 0.2f * tt) + cneg;          // LeakyReLU (log2-scaled) - m' - 1000
      pv[s] = __builtin_amdgcn_exp2f(fmaf((float)aa, 1000.0f, u));  // masked -> exact 0
    }
    if (ks < 31) {  // prefetch next step while this one computes
      ca0 = *(const i32x4*)(arow + (ks + 1) * 32);
      ca1 = *(const i32x4*)(arow + (ks + 1) * 32 + 4);
      cd0 = *(const f32x4*)(Dh + (ks + 1) * 32);
      cd1 = *(const f32x4*)(Dh + (ks + 1) * 32 + 4);
    }
    dsum += ((pv[0] + pv[1]) + (pv[2] + pv[3])) + ((pv[4] + pv[5]) + (pv[6] + pv[7]));
    union { h16x2 h2[4]; h16x8 h8; } up;
    up.h2[0] = __builtin_amdgcn_cvt_pkrtz(pv[0], pv[1]);
    up.h2[1] = __builtin_amdgcn_cvt_pkrtz(pv[2], pv[3]);
    up.h2[2] = __builtin_amdgcn_cvt_pkrtz(pv[4], pv[5]);
    up.h2[3] = __builtin_amdgcn_cvt_pkrtz(pv[6], pv[7]);
    const __fp16* hb = hTh + (size_t)ks * 4096;
#pragma unroll
    for (int nf = 0; nf < 8; ++nf) {
      h16x8 Bf = *(const h16x8*)(hb + nf * 512);   // col = nf*16 + c16
      acc[nf] = __builtin_amdgcn_mfma_f32_16x16x32_f16(up.h8, Bf, acc[nf], 0, 0, 0);
    }
  }
  // denom: reduce the 4 k-groups (lanes sharing c16)
  dsum += __shfl_xor(dsum, 16);
  dsum += __shfl_xor(dsum, 32);
  if (g4 == 0) DEN[(size_t)(js * 2 + h) * NN + row] = dsum;
  // C layout (16x16): col = c16, crow = g4*4 + r
  __fp16* nb = NUM + ((size_t)(js * 2 + h) * NN + i0 + rg * 16 + g4 * 4) * 128 + c16;
#pragma unroll
  for (int nf = 0; nf < 8; ++nf)
#pragma unroll
    for (int r = 0; r < 4; ++r)
      nb[(size_t)r * 128 + nf * 16] = (__fp16)acc[nf][r];
}

// ---------------- K3: merge js partials, combine heads, ELU
__global__ __launch_bounds__(256) void k3_out(const __fp16* __restrict__ NUM,
                                              const float* __restrict__ DEN,
                                              float* __restrict__ out) {
  int gid = blockIdx.x * 256 + threadIdx.x;  // 262144
  int i = gid >> 5;
  int c4 = (gid & 31) * 4;
  f32x4 n1 = {0.f, 0.f, 0.f, 0.f}, n2 = {0.f, 0.f, 0.f, 0.f};
  float d1 = 0.f, d2 = 0.f;
#pragma unroll
  for (int js = 0; js < 8; ++js) {
    h16x4 a1v = *(const h16x4*)(NUM + ((size_t)(js * 2 + 0) * NN + i) * 128 + c4);
    h16x4 a2v = *(const h16x4*)(NUM + ((size_t)(js * 2 + 1) * NN + i) * 128 + c4);
#pragma unroll
    for (int e = 0; e < 4; ++e) { n1[e] += (float)a1v[e]; n2[e] += (float)a2v[e]; }
    d1 += DEN[(size_t)(js * 2 + 0) * NN + i];
    d2 += DEN[(size_t)(js * 2 + 1) * NN + i];
  }
  float r1 = 1.0f / d1, r2 = 0.5f / d2;
  f32x4 o;
#pragma unroll
  for (int e = 0; e < 4; ++e) {
    float x = n1[e] * r1 + n2[e] * r2;
    o[e] = x > 0.f ? x : (exp2f(x * LOG2E) - 1.0f);
  }
  *(f32x4*)(out + (size_t)i * 128 + c4) = o;
}

extern "C" void kernel_launch(void* const* d_in, const int* in_sizes, int n_in,
                              void* d_out, int out_size, void* d_ws, size_t ws_size,
                              hipStream_t stream) {
  const float* inp = (const float*)d_in[0];
  const int* adj = (const int*)d_in[1];
  const float* W1 = (const float*)d_in[2];
  const float* a1 = (const float*)d_in[3];
  const float* W2 = (const float*)d_in[4];
  const float* a2 = (const float*)d_in[5];
  float* out = (float*)d_out;
  char* ws = (char*)d_ws;
  // ws layout (~38.5 MB):
  __fp16* WT = (__fp16*)(ws);                  // 131072 B
  __fp16* hT = (__fp16*)(ws + 131072);         // 4 MB
  float* S = (float*)(ws + 4325376);           // 64 KB
  float* D = (float*)(ws + 4390912);           // 64 KB
  float* GM = (float*)(ws + 4456448);          // 256 B
  __fp16* NUM = (__fp16*)(ws + 4456704);       // 32 MB (16 partials, f16)
  float* DEN = (float*)(ws + 38011136);        // 512 KB

  k0_wt<<<dim3(32), dim3(256), 0, stream>>>(W1, W2, WT);
  k1_h<<<dim3(256), dim3(128), 0, stream>>>(inp, WT, a1, a2, hT, S, D);
  k1c_gmax<<<dim3(1), dim3(256), 0, stream>>>(D, GM);
  k2_attn<<<dim3(2048), dim3(256), 0, stream>>>(adj, hT, S, D, GM, NUM, DEN);
  k3_out<<<dim3(1024), dim3(256), 0, stream>>>(NUM, DEN, out);
}

// Round 5
// 236.444 us; speedup vs baseline: 1.5964x; 1.5964x over previous
//
#include <hip/hip_runtime.h>
#include <hip/hip_fp16.h>

#define NN 8192
#define INF 256
#define OUTF 128
#define LOG2E 1.44269504088896340736f

typedef float f32x4 __attribute__((ext_vector_type(4)));
typedef float f32x16 __attribute__((ext_vector_type(16)));
typedef __fp16 h16x8 __attribute__((ext_vector_type(8)));
typedef __fp16 h16x4 __attribute__((ext_vector_type(4)));
typedef __fp16 h16x2 __attribute__((ext_vector_type(2)));
typedef int i32x4 __attribute__((ext_vector_type(4)));

// ---------------- K0: W (256x128 f32) -> WT_perm f16 (for K1's 32x32x16 MFMA)
__global__ __launch_bounds__(256) void k0_wt(const float* __restrict__ W1,
                                             const float* __restrict__ W2,
                                             __fp16* __restrict__ WT) {
  int m = blockIdx.x * 256 + threadIdx.x;  // 8192 chunks of 16B
  int h = m >> 12;
  int r = m & 4095;
  int c = r >> 5;
  int kb = (r >> 1) & 15;
  int hh = r & 1;
  const float* W = h ? W2 : W1;
  float v[8];
#pragma unroll
  for (int s = 0; s < 8; ++s) {
    int koff = 4 * hh + (s & 3) + 8 * (s >> 2);
    v[s] = W[(kb * 16 + koff) * OUTF + c];
  }
  union { h16x2 h2[4]; i32x4 q; } u;
  u.h2[0] = __builtin_amdgcn_cvt_pkrtz(v[0], v[1]);
  u.h2[1] = __builtin_amdgcn_cvt_pkrtz(v[2], v[3]);
  u.h2[2] = __builtin_amdgcn_cvt_pkrtz(v[4], v[5]);
  u.h2[3] = __builtin_amdgcn_cvt_pkrtz(v[6], v[7]);
  *(i32x4*)(WT + (size_t)h * 32768 + c * 256 + kb * 16 + hh * 8) = u.q;
}

// ---------------- K1: h = inp@W via MFMA; emits hT_perm16 (16x16x32 B-frag layout),
// src' and dst' scaled by log2e
__global__ __launch_bounds__(128) void k1_h(
    const float* __restrict__ inp, const __fp16* __restrict__ WT,
    const float* __restrict__ a1, const float* __restrict__ a2,
    __fp16* __restrict__ hT, float* __restrict__ S, float* __restrict__ D) {
  __shared__ __align__(16) float hl[2][32][136];
  int tid = threadIdx.x;
  int w = tid >> 6;           // wave = head
  int l = tid & 63;
  int lr = l & 31, g = l >> 5;
  int i0 = blockIdx.x * 32;
  const __fp16* WTh = WT + (size_t)w * 32768;
  f32x16 acc[4];
#pragma unroll
  for (int nf = 0; nf < 4; ++nf)
#pragma unroll
    for (int e = 0; e < 16; ++e) acc[nf][e] = 0.0f;
  const float* ip = inp + (size_t)(i0 + lr) * INF;
#pragma unroll
  for (int kb = 0; kb < 16; ++kb) {
    f32x4 q0 = *(const f32x4*)(ip + kb * 16 + 4 * g);
    f32x4 q1 = *(const f32x4*)(ip + kb * 16 + 8 + 4 * g);
    union { h16x2 h2[4]; h16x8 h8; } ua;
    ua.h2[0] = __builtin_amdgcn_cvt_pkrtz(q0[0], q0[1]);
    ua.h2[1] = __builtin_amdgcn_cvt_pkrtz(q0[2], q0[3]);
    ua.h2[2] = __builtin_amdgcn_cvt_pkrtz(q1[0], q1[1]);
    ua.h2[3] = __builtin_amdgcn_cvt_pkrtz(q1[2], q1[3]);
#pragma unroll
    for (int nf = 0; nf < 4; ++nf) {
      h16x8 b = *(const h16x8*)(WTh + (nf * 32 + lr) * 256 + kb * 16 + g * 8);
      acc[nf] = __builtin_amdgcn_mfma_f32_32x32x16_f16(ua.h8, b, acc[nf], 0, 0, 0);
    }
  }
#pragma unroll
  for (int nf = 0; nf < 4; ++nf)
#pragma unroll
    for (int r = 0; r < 16; ++r) {
      int row = (r & 3) + 8 * (r >> 2) + 4 * g;
      hl[w][row][nf * 32 + lr] = acc[nf][r];
    }
  __syncthreads();
  const float* av = w ? a2 : a1;
  float s = 0.f, d = 0.f;
#pragma unroll
  for (int cc = 0; cc < 64; cc += 4) {
    int c = g * 64 + cc;
    f32x4 hv = *(const f32x4*)&hl[w][lr][c];
    f32x4 as = *(const f32x4*)(av + c);
    f32x4 ad = *(const f32x4*)(av + 128 + c);
    s += hv[0] * as[0] + hv[1] * as[1] + hv[2] * as[2] + hv[3] * as[3];
    d += hv[0] * ad[0] + hv[1] * ad[1] + hv[2] * ad[2] + hv[3] * ad[3];
  }
  s += __shfl_xor(s, 32);
  d += __shfl_xor(d, 32);
  if (g == 0) {
    S[(size_t)w * NN + i0 + lr] = s * LOG2E;
    D[(size_t)w * NN + i0 + lr] = d * LOG2E;
  }
  // hT_perm16: [head][jb32][col128][g4][8slots] f16; jb32 = blockIdx.x (rows i0..i0+31)
  __fp16* hTh = hT + (size_t)w * (NN * OUTF) + (size_t)blockIdx.x * 4096;
#pragma unroll
  for (int it = 0; it < 8; ++it) {
    int m = it * 64 + l;            // 512 16B-chunks
    int col = m & 127, gw = m >> 7; // gw = k-group 0..3
    float v[8];
#pragma unroll
    for (int s2 = 0; s2 < 8; ++s2) v[s2] = hl[w][gw * 8 + s2][col];
    union { h16x2 h2[4]; i32x4 q; } u2;
    u2.h2[0] = __builtin_amdgcn_cvt_pkrtz(v[0], v[1]);
    u2.h2[1] = __builtin_amdgcn_cvt_pkrtz(v[2], v[3]);
    u2.h2[2] = __builtin_amdgcn_cvt_pkrtz(v[4], v[5]);
    u2.h2[3] = __builtin_amdgcn_cvt_pkrtz(v[6], v[7]);
    *(i32x4*)(hTh + col * 32 + gw * 8) = u2.q;
  }
}

// ---------------- K1c: gmax' per head
__global__ __launch_bounds__(256) void k1c_gmax(const float* __restrict__ D,
                                                float* __restrict__ GM) {
  __shared__ float r1[256], r2[256];
  int t = threadIdx.x;
  float m1 = -1e30f, m2 = -1e30f;
  for (int i = t; i < NN; i += 256) {
    m1 = fmaxf(m1, D[i]);
    m2 = fmaxf(m2, D[NN + i]);
  }
  r1[t] = m1; r2[t] = m2;
  __syncthreads();
  for (int s = 128; s > 0; s >>= 1) {
    if (t < s) { r1[t] = fmaxf(r1[t], r1[t + s]); r2[t] = fmaxf(r2[t], r2[t + s]); }
    __syncthreads();
  }
  if (t == 0) { GM[0] = r1[0]; GM[1] = r2[0]; }
}

// ---------------- K2: fully fused adj-stream + mask + softmax + PV. No LDS.
// grid 2048 = 256 rowblocks(BM=32) x 8 js; 4 waves = 2 heads x 2 rowgroups of 16.
// launch_bounds (256,4): r4's (256,6) forced VGPR=40 -> scratch spills (WRITE 191MB).
__global__ __launch_bounds__(256, 4) void k2_attn(
    const int* __restrict__ adj, const __fp16* __restrict__ hT,
    const float* __restrict__ S, const float* __restrict__ D,
    const float* __restrict__ GM, __fp16* __restrict__ NUM, float* __restrict__ DEN) {
  int tid = threadIdx.x;
  int w = tid >> 6;
  int l = tid & 63;
  int c16 = l & 15, g4 = l >> 4;
  int h = w >> 1, rg = w & 1;
  int rb = blockIdx.x >> 3, js = blockIdx.x & 7;
  int i0 = rb * 32;
  int row = i0 + rg * 16 + c16;
  float sf = S[(size_t)h * NN + row];
  float gm = GM[h];
  float v0 = sf + gm;
  float cneg = -fmaxf(v0, 0.2f * v0) - 1000.0f;  // arg = LRelu' + cneg + adj*1000
  const __fp16* hTh = hT + (size_t)h * (NN * OUTF) + (size_t)(js * 32) * 4096 +
                      c16 * 32 + g4 * 8;
  const float* Dh = D + (size_t)h * NN + js * 1024 + g4 * 8;
  const int* arow = adj + (size_t)row * NN + js * 1024 + g4 * 8;

  f32x4 acc[8];
#pragma unroll
  for (int nf = 0; nf < 8; ++nf) acc[nf] = {0.f, 0.f, 0.f, 0.f};
  float dsum = 0.f;

  // adj register prefetch, 1 ks-step deep (the HBM stream)
  i32x4 ca0 = *(const i32x4*)(arow);
  i32x4 ca1 = *(const i32x4*)(arow + 4);

#pragma unroll 2
  for (int ks = 0; ks < 32; ++ks) {
    f32x4 d0 = *(const f32x4*)(Dh + ks * 32);      // dst' (L1/L2-resident, no prefetch)
    f32x4 d1 = *(const f32x4*)(Dh + ks * 32 + 4);
    i32x4 aa0 = ca0, aa1 = ca1;
    if (ks < 31) {  // prefetch next adj step while this one computes
      ca0 = *(const i32x4*)(arow + (ks + 1) * 32);
      ca1 = *(const i32x4*)(arow + (ks + 1) * 32 + 4);
    }
    float pv[8];
#pragma unroll
    for (int s = 0; s < 8; ++s) {
      float dd = (s < 4) ? d0[s] : d1[s - 4];
      int aa = (s < 4) ? aa0[s] : aa1[s - 4];
      float tt = sf + dd;
      float u = fmaxf(tt, 0.2f * tt) + cneg;          // LeakyReLU (log2-scaled) - m' - 1000
      pv[s] = __builtin_amdgcn_exp2f(fmaf((float)aa, 1000.0f, u));  // masked -> exact 0
    }
    dsum += ((pv[0] + pv[1]) + (pv[2] + pv[3])) + ((pv[4] + pv[5]) + (pv[6] + pv[7]));
    union { h16x2 h2[4]; h16x8 h8; } up;
    up.h2[0] = __builtin_amdgcn_cvt_pkrtz(pv[0], pv[1]);
    up.h2[1] = __builtin_amdgcn_cvt_pkrtz(pv[2], pv[3]);
    up.h2[2] = __builtin_amdgcn_cvt_pkrtz(pv[4], pv[5]);
    up.h2[3] = __builtin_amdgcn_cvt_pkrtz(pv[6], pv[7]);
    const __fp16* hb = hTh + (size_t)ks * 4096;
#pragma unroll
    for (int nf = 0; nf < 8; ++nf) {
      h16x8 Bf = *(const h16x8*)(hb + nf * 512);   // col = nf*16 + c16
      acc[nf] = __builtin_amdgcn_mfma_f32_16x16x32_f16(up.h8, Bf, acc[nf], 0, 0, 0);
    }
  }
  // denom: reduce the 4 k-groups (lanes sharing c16)
  dsum += __shfl_xor(dsum, 16);
  dsum += __shfl_xor(dsum, 32);
  if (g4 == 0) DEN[(size_t)(js * 2 + h) * NN + row] = dsum;
  // C layout (16x16): col = c16, crow = g4*4 + r
  __fp16* nb = NUM + ((size_t)(js * 2 + h) * NN + i0 + rg * 16 + g4 * 4) * 128 + c16;
#pragma unroll
  for (int nf = 0; nf < 8; ++nf)
#pragma unroll
    for (int r = 0; r < 4; ++r)
      nb[(size_t)r * 128 + nf * 16] = (__fp16)acc[nf][r];
}

// ---------------- K3: merge js partials, combine heads, ELU
__global__ __launch_bounds__(256) void k3_out(const __fp16* __restrict__ NUM,
                                              const float* __restrict__ DEN,
                                              float* __restrict__ out) {
  int gid = blockIdx.x * 256 + threadIdx.x;  // 262144
  int i = gid >> 5;
  int c4 = (gid & 31) * 4;
  f32x4 n1 = {0.f, 0.f, 0.f, 0.f}, n2 = {0.f, 0.f, 0.f, 0.f};
  float d1 = 0.f, d2 = 0.f;
#pragma unroll
  for (int js = 0; js < 8; ++js) {
    h16x4 a1v = *(const h16x4*)(NUM + ((size_t)(js * 2 + 0) * NN + i) * 128 + c4);
    h16x4 a2v = *(const h16x4*)(NUM + ((size_t)(js * 2 + 1) * NN + i) * 128 + c4);
#pragma unroll
    for (int e = 0; e < 4; ++e) { n1[e] += (float)a1v[e]; n2[e] += (float)a2v[e]; }
    d1 += DEN[(size_t)(js * 2 + 0) * NN + i];
    d2 += DEN[(size_t)(js * 2 + 1) * NN + i];
  }
  float r1 = 1.0f / d1, r2 = 0.5f / d2;
  f32x4 o;
#pragma unroll
  for (int e = 0; e < 4; ++e) {
    float x = n1[e] * r1 + n2[e] * r2;
    o[e] = x > 0.f ? x : (exp2f(x * LOG2E) - 1.0f);
  }
  *(f32x4*)(out + (size_t)i * 128 + c4) = o;
}

extern "C" void kernel_launch(void* const* d_in, const int* in_sizes, int n_in,
                              void* d_out, int out_size, void* d_ws, size_t ws_size,
                              hipStream_t stream) {
  const float* inp = (const float*)d_in[0];
  const int* adj = (const int*)d_in[1];
  const float* W1 = (const float*)d_in[2];
  const float* a1 = (const float*)d_in[3];
  const float* W2 = (const float*)d_in[4];
  const float* a2 = (const float*)d_in[5];
  float* out = (float*)d_out;
  char* ws = (char*)d_ws;
  // ws layout (~38.5 MB):
  __fp16* WT = (__fp16*)(ws);                  // 131072 B
  __fp16* hT = (__fp16*)(ws + 131072);         // 4 MB
  float* S = (float*)(ws + 4325376);           // 64 KB
  float* D = (float*)(ws + 4390912);           // 64 KB
  float* GM = (float*)(ws + 4456448);          // 256 B
  __fp16* NUM = (__fp16*)(ws + 4456704);       // 32 MB (16 partials, f16)
  float* DEN = (float*)(ws + 38011136);        // 512 KB

  k0_wt<<<dim3(32), dim3(256), 0, stream>>>(W1, W2, WT);
  k1_h<<<dim3(256), dim3(128), 0, stream>>>(inp, WT, a1, a2, hT, S, D);
  k1c_gmax<<<dim3(1), dim3(256), 0, stream>>>(D, GM);
  k2_attn<<<dim3(2048), dim3(256), 0, stream>>>(adj, hT, S, D, GM, NUM, DEN);
  k3_out<<<dim3(1024), dim3(256), 0, stream>>>(NUM, DEN, out);
}

// Round 6
// 172.686 us; speedup vs baseline: 2.1858x; 1.3692x over previous
//
#include <hip/hip_runtime.h>
#include <hip/hip_fp16.h>

#define NN 8192
#define INF 256
#define OUTF 128
#define LOG2E 1.44269504088896340736f

typedef float f32x4 __attribute__((ext_vector_type(4)));
typedef float f32x16 __attribute__((ext_vector_type(16)));
typedef __fp16 h16x8 __attribute__((ext_vector_type(8)));
typedef __fp16 h16x4 __attribute__((ext_vector_type(4)));
typedef __fp16 h16x2 __attribute__((ext_vector_type(2)));
typedef int i32x4 __attribute__((ext_vector_type(4)));

__device__ __forceinline__ void gload_lds16(const void* g, void* l) {
  __builtin_amdgcn_global_load_lds(
      (const __attribute__((address_space(1))) unsigned int*)g,
      (__attribute__((address_space(3))) unsigned int*)l, 16, 0, 0);
}

// ---------------- KB: adj int32 -> u16 bitmask, TRANSPOSED [j16][row] (8 MB).
// Each lane: 16 contiguous ints (4 x i32x4) -> perfectly streaming reads.
__global__ __launch_bounds__(256) void kb_pack(const int* __restrict__ adj,
                                               unsigned short* __restrict__ adjbT) {
  int gid = blockIdx.x * 256 + threadIdx.x;   // chunk id base
#pragma unroll
  for (int it = 0; it < 8; ++it) {
    size_t c = (size_t)it * 524288 + gid;     // u16-chunk index, 4M total
    size_t base = c * 16;                     // element index
    int row = (int)(base >> 13);
    int j16 = (int)(base & 8191) >> 4;
    const int* p = adj + base;
    i32x4 v0 = *(const i32x4*)(p);
    i32x4 v1 = *(const i32x4*)(p + 4);
    i32x4 v2 = *(const i32x4*)(p + 8);
    i32x4 v3 = *(const i32x4*)(p + 12);
    unsigned int b = 0;
#pragma unroll
    for (int k = 0; k < 4; ++k) {
      b |= (v0[k] != 0 ? 1u : 0u) << k;
      b |= (v1[k] != 0 ? 1u : 0u) << (4 + k);
      b |= (v2[k] != 0 ? 1u : 0u) << (8 + k);
      b |= (v3[k] != 0 ? 1u : 0u) << (12 + k);
    }
    adjbT[(size_t)j16 * NN + row] = (unsigned short)b;
  }
}

// ---------------- K0: W (256x128 f32) -> WT_perm f16 (for K1's 32x32x16 MFMA)
__global__ __launch_bounds__(256) void k0_wt(const float* __restrict__ W1,
                                             const float* __restrict__ W2,
                                             __fp16* __restrict__ WT) {
  int m = blockIdx.x * 256 + threadIdx.x;  // 8192 chunks of 16B
  int h = m >> 12;
  int r = m & 4095;
  int c = r >> 5;
  int kb = (r >> 1) & 15;
  int hh = r & 1;
  const float* W = h ? W2 : W1;
  float v[8];
#pragma unroll
  for (int s = 0; s < 8; ++s) {
    int koff = 4 * hh + (s & 3) + 8 * (s >> 2);
    v[s] = W[(kb * 16 + koff) * OUTF + c];
  }
  union { h16x2 h2[4]; i32x4 q; } u;
  u.h2[0] = __builtin_amdgcn_cvt_pkrtz(v[0], v[1]);
  u.h2[1] = __builtin_amdgcn_cvt_pkrtz(v[2], v[3]);
  u.h2[2] = __builtin_amdgcn_cvt_pkrtz(v[4], v[5]);
  u.h2[3] = __builtin_amdgcn_cvt_pkrtz(v[6], v[7]);
  *(i32x4*)(WT + (size_t)h * 32768 + c * 256 + kb * 16 + hh * 8) = u.q;
}

// ---------------- K1: h = inp@W via MFMA; emits hT2 in 32x32x16 B-frag layout:
// [head][j16][nf4][lane64][slot8] f16; also src'/dst' scaled by log2e.
__global__ __launch_bounds__(128) void k1_h(
    const float* __restrict__ inp, const __fp16* __restrict__ WT,
    const float* __restrict__ a1, const float* __restrict__ a2,
    __fp16* __restrict__ hT2, float* __restrict__ S, float* __restrict__ D) {
  __shared__ __align__(16) float hl[2][32][136];
  int tid = threadIdx.x;
  int w = tid >> 6;           // wave = head
  int l = tid & 63;
  int lr = l & 31, g = l >> 5;
  int i0 = blockIdx.x * 32;
  const __fp16* WTh = WT + (size_t)w * 32768;
  f32x16 acc[4];
#pragma unroll
  for (int nf = 0; nf < 4; ++nf)
#pragma unroll
    for (int e = 0; e < 16; ++e) acc[nf][e] = 0.0f;
  const float* ip = inp + (size_t)(i0 + lr) * INF;
#pragma unroll
  for (int kb = 0; kb < 16; ++kb) {
    f32x4 q0 = *(const f32x4*)(ip + kb * 16 + 4 * g);
    f32x4 q1 = *(const f32x4*)(ip + kb * 16 + 8 + 4 * g);
    union { h16x2 h2[4]; h16x8 h8; } ua;
    ua.h2[0] = __builtin_amdgcn_cvt_pkrtz(q0[0], q0[1]);
    ua.h2[1] = __builtin_amdgcn_cvt_pkrtz(q0[2], q0[3]);
    ua.h2[2] = __builtin_amdgcn_cvt_pkrtz(q1[0], q1[1]);
    ua.h2[3] = __builtin_amdgcn_cvt_pkrtz(q1[2], q1[3]);
#pragma unroll
    for (int nf = 0; nf < 4; ++nf) {
      h16x8 b = *(const h16x8*)(WTh + (nf * 32 + lr) * 256 + kb * 16 + g * 8);
      acc[nf] = __builtin_amdgcn_mfma_f32_32x32x16_f16(ua.h8, b, acc[nf], 0, 0, 0);
    }
  }
#pragma unroll
  for (int nf = 0; nf < 4; ++nf)
#pragma unroll
    for (int r = 0; r < 16; ++r) {
      int row = (r & 3) + 8 * (r >> 2) + 4 * g;
      hl[w][row][nf * 32 + lr] = acc[nf][r];
    }
  __syncthreads();
  const float* av = w ? a2 : a1;
  float s = 0.f, d = 0.f;
#pragma unroll
  for (int cc = 0; cc < 64; cc += 4) {
    int c = g * 64 + cc;
    f32x4 hv = *(const f32x4*)&hl[w][lr][c];
    f32x4 as = *(const f32x4*)(av + c);
    f32x4 ad = *(const f32x4*)(av + 128 + c);
    s += hv[0] * as[0] + hv[1] * as[1] + hv[2] * as[2] + hv[3] * as[3];
    d += hv[0] * ad[0] + hv[1] * ad[1] + hv[2] * ad[2] + hv[3] * ad[3];
  }
  s += __shfl_xor(s, 32);
  d += __shfl_xor(d, 32);
  if (g == 0) {
    S[(size_t)w * NN + i0 + lr] = s * LOG2E;
    D[(size_t)w * NN + i0 + lr] = d * LOG2E;
  }
  // hT2 emission: per head, 2 j16-blocks x 256 chunks(16B) = 512; 64 lanes x 8 iters.
  __fp16* hTh = hT2 + (size_t)w * (NN * OUTF);
#pragma unroll
  for (int it = 0; it < 8; ++it) {
    int id = it * 64 + l;           // [0,512)
    int jb = id >> 8;
    int sub = id & 255;
    int nf = sub >> 6, lq = sub & 63;
    int lqr = lq & 31, lqg = lq >> 5;
    float v[8];
#pragma unroll
    for (int s2 = 0; s2 < 8; ++s2) {
      int kloc = 4 * lqg + (s2 & 3) + 8 * (s2 >> 2);   // MFMA k-map (A/B identical)
      v[s2] = hl[w][jb * 16 + kloc][nf * 32 + lqr];
    }
    union { h16x2 h2[4]; i32x4 q; } u2;
    u2.h2[0] = __builtin_amdgcn_cvt_pkrtz(v[0], v[1]);
    u2.h2[1] = __builtin_amdgcn_cvt_pkrtz(v[2], v[3]);
    u2.h2[2] = __builtin_amdgcn_cvt_pkrtz(v[4], v[5]);
    u2.h2[3] = __builtin_amdgcn_cvt_pkrtz(v[6], v[7]);
    *(i32x4*)(hTh + (size_t)((i0 >> 4) + jb) * 2048 + sub * 8) = u2.q;
  }
}

// ---------------- K1c: gmax' per head
__global__ __launch_bounds__(256) void k1c_gmax(const float* __restrict__ D,
                                                float* __restrict__ GM) {
  __shared__ float r1[256], r2[256];
  int t = threadIdx.x;
  float m1 = -1e30f, m2 = -1e30f;
  for (int i = t; i < NN; i += 256) {
    m1 = fmaxf(m1, D[i]);
    m2 = fmaxf(m2, D[NN + i]);
  }
  r1[t] = m1; r2[t] = m2;
  __syncthreads();
  for (int s = 128; s > 0; s >>= 1) {
    if (t < s) { r1[t] = fmaxf(r1[t], r1[t + s]); r2[t] = fmaxf(r2[t], r2[t + s]); }
    __syncthreads();
  }
  if (t == 0) { GM[0] = r1[0]; GM[1] = r2[0]; }
}

// ---------------- K2: bitmask softmax + PV, 32x32x16 MFMA, LDS-staged B-frags.
// grid 1024 = 128 rowblocks(BM=64) x 8 js; 4 waves = 2 heads x 2 rowgroups(32).
__global__ __launch_bounds__(256, 4) void k2_attn(
    const unsigned short* __restrict__ adjbT, const __fp16* __restrict__ hT2,
    const float* __restrict__ S, const float* __restrict__ D,
    const float* __restrict__ GM, __fp16* __restrict__ NUM, float* __restrict__ DEN) {
  __shared__ __align__(16) char smem[32768];  // 2 buf x (2 kk x 2 heads x 4KB)
  int tid = threadIdx.x;
  int w = tid >> 6;
  int l = tid & 63;
  int lr = l & 31, g2 = l >> 5;
  int h = w >> 1, rq = w & 1;
  int rb = blockIdx.x >> 3, js = blockIdx.x & 7;
  int i0 = rb * 64;
  int jwin = js * 1024, jw16 = js * 64;
  int row = i0 + rq * 32 + lr;
  float sf = S[(size_t)h * NN + row];
  float gm = GM[h];
  float v0 = sf + gm;
  float cneg = -fmaxf(v0, 0.2f * v0) - 1000.0f;
  const float* Dh = D + (size_t)h * NN + jwin + 4 * g2;

  f32x16 acc[4];
#pragma unroll
  for (int nf = 0; nf < 4; ++nf)
#pragma unroll
    for (int e = 0; e < 16; ++e) acc[nf][e] = 0.0f;
  float dsum = 0.f;

  auto STAGE = [&](int jstep, int b) {
#pragma unroll
    for (int q = 0; q < 4; ++q) {
      int kk_l = q >> 1, hh = q & 1;
      const __fp16* gs = hT2 + (size_t)hh * (NN * OUTF) +
                         (size_t)(jw16 + jstep * 2 + kk_l) * 2048 + tid * 8;
      char* ld = smem + b * 16384 + q * 4096 + (w * 64) * 16 + l * 16;
      gload_lds16(gs, ld);
    }
  };

  // mask u16 prefetch (2 K-steps ahead = 1 jstep)
  unsigned short mb0 = adjbT[(size_t)(jw16 + 0) * NN + row];
  unsigned short mb1 = adjbT[(size_t)(jw16 + 1) * NN + row];

  STAGE(0, 0);
  __syncthreads();

  int b = 0;
  for (int jstep = 0; jstep < 32; ++jstep) {
    if (jstep < 31) STAGE(jstep + 1, b ^ 1);
    unsigned int bits[2] = {mb0, mb1};
    if (jstep < 31) {
      mb0 = adjbT[(size_t)(jw16 + jstep * 2 + 2) * NN + row];
      mb1 = adjbT[(size_t)(jw16 + jstep * 2 + 3) * NN + row];
    }
#pragma unroll
    for (int kk = 0; kk < 2; ++kk) {
      int kkg = jstep * 2 + kk;
      f32x4 d0 = *(const f32x4*)(Dh + kkg * 16);
      f32x4 d1 = *(const f32x4*)(Dh + kkg * 16 + 8);
      unsigned int bt = bits[kk];
      float pv[8];
#pragma unroll
      for (int s = 0; s < 8; ++s) {
        float dd = (s < 4) ? d0[s] : d1[s - 4];
        int kloc = 4 * g2 + (s & 3) + 8 * (s >> 2);
        float tt = sf + dd;
        float u = fmaxf(tt, 0.2f * tt) + cneg;
        float bf = (float)((bt >> kloc) & 1u);
        pv[s] = __builtin_amdgcn_exp2f(fmaf(bf, 1000.0f, u));
      }
      dsum += ((pv[0] + pv[1]) + (pv[2] + pv[3])) + ((pv[4] + pv[5]) + (pv[6] + pv[7]));
      union { h16x2 h2[4]; h16x8 h8; } up;
      up.h2[0] = __builtin_amdgcn_cvt_pkrtz(pv[0], pv[1]);
      up.h2[1] = __builtin_amdgcn_cvt_pkrtz(pv[2], pv[3]);
      up.h2[2] = __builtin_amdgcn_cvt_pkrtz(pv[4], pv[5]);
      up.h2[3] = __builtin_amdgcn_cvt_pkrtz(pv[6], pv[7]);
      const char* lb = smem + b * 16384 + (kk * 2 + h) * 4096 + l * 16;
#pragma unroll
      for (int nf = 0; nf < 4; ++nf) {
        h16x8 Bf = *(const h16x8*)(lb + nf * 1024);
        acc[nf] = __builtin_amdgcn_mfma_f32_32x32x16_f16(up.h8, Bf, acc[nf], 0, 0, 0);
      }
    }
    __syncthreads();
    b ^= 1;
  }

  // denom: lanes l and l+32 share a row
  dsum += __shfl_xor(dsum, 32);
  if (g2 == 0) DEN[(size_t)(js * 2 + h) * NN + row] = dsum;
  // C layout (32x32): col = lr, crow = (r&3)+8*(r>>2)+4*g2
  __fp16* nb = NUM + ((size_t)(js * 2 + h) * NN + i0 + rq * 32) * 128 + lr;
#pragma unroll
  for (int nf = 0; nf < 4; ++nf)
#pragma unroll
    for (int r = 0; r < 16; ++r) {
      int crow = (r & 3) + 8 * (r >> 2) + 4 * g2;
      nb[(size_t)crow * 128 + nf * 32] = (__fp16)acc[nf][r];
    }
}

// ---------------- K3: merge js partials, combine heads, ELU
__global__ __launch_bounds__(256) void k3_out(const __fp16* __restrict__ NUM,
                                              const float* __restrict__ DEN,
                                              float* __restrict__ out) {
  int gid = blockIdx.x * 256 + threadIdx.x;  // 262144
  int i = gid >> 5;
  int c4 = (gid & 31) * 4;
  f32x4 n1 = {0.f, 0.f, 0.f, 0.f}, n2 = {0.f, 0.f, 0.f, 0.f};
  float d1 = 0.f, d2 = 0.f;
#pragma unroll
  for (int js = 0; js < 8; ++js) {
    h16x4 a1v = *(const h16x4*)(NUM + ((size_t)(js * 2 + 0) * NN + i) * 128 + c4);
    h16x4 a2v = *(const h16x4*)(NUM + ((size_t)(js * 2 + 1) * NN + i) * 128 + c4);
#pragma unroll
    for (int e = 0; e < 4; ++e) { n1[e] += (float)a1v[e]; n2[e] += (float)a2v[e]; }
    d1 += DEN[(size_t)(js * 2 + 0) * NN + i];
    d2 += DEN[(size_t)(js * 2 + 1) * NN + i];
  }
  float r1 = 1.0f / d1, r2 = 0.5f / d2;
  f32x4 o;
#pragma unroll
  for (int e = 0; e < 4; ++e) {
    float x = n1[e] * r1 + n2[e] * r2;
    o[e] = x > 0.f ? x : (exp2f(x * LOG2E) - 1.0f);
  }
  *(f32x4*)(out + (size_t)i * 128 + c4) = o;
}

extern "C" void kernel_launch(void* const* d_in, const int* in_sizes, int n_in,
                              void* d_out, int out_size, void* d_ws, size_t ws_size,
                              hipStream_t stream) {
  const float* inp = (const float*)d_in[0];
  const int* adj = (const int*)d_in[1];
  const float* W1 = (const float*)d_in[2];
  const float* a1 = (const float*)d_in[3];
  const float* W2 = (const float*)d_in[4];
  const float* a2 = (const float*)d_in[5];
  float* out = (float*)d_out;
  char* ws = (char*)d_ws;
  // ws layout (~46.9 MB):
  __fp16* WT = (__fp16*)(ws);                              // 128 KB
  __fp16* hT2 = (__fp16*)(ws + 131072);                    // 4 MB
  float* S = (float*)(ws + 4325376);                       // 64 KB
  float* D = (float*)(ws + 4390912);                       // 64 KB
  float* GM = (float*)(ws + 4456448);                      // 256 B
  unsigned short* adjbT = (unsigned short*)(ws + 4456704); // 8 MB
  __fp16* NUM = (__fp16*)(ws + 12845312);                  // 32 MB
  float* DEN = (float*)(ws + 46399744);                    // 512 KB

  kb_pack<<<dim3(2048), dim3(256), 0, stream>>>(adj, adjbT);
  k0_wt<<<dim3(32), dim3(256), 0, stream>>>(W1, W2, WT);
  k1_h<<<dim3(256), dim3(128), 0, stream>>>(inp, WT, a1, a2, hT2, S, D);
  k1c_gmax<<<dim3(1), dim3(256), 0, stream>>>(D, GM);
  k2_attn<<<dim3(1024), dim3(256), 0, stream>>>(adjbT, hT2, S, D, GM, NUM, DEN);
  k3_out<<<dim3(1024), dim3(256), 0, stream>>>(NUM, DEN, out);
}

// Round 7
// 147.139 us; speedup vs baseline: 2.5653x; 1.1736x over previous
//
#include <hip/hip_runtime.h>
#include <hip/hip_fp16.h>

#define NN 8192
#define INF 256
#define OUTF 128
#define LOG2E 1.44269504088896340736f

typedef float f32x4 __attribute__((ext_vector_type(4)));
typedef float f32x16 __attribute__((ext_vector_type(16)));
typedef __fp16 h16x8 __attribute__((ext_vector_type(8)));
typedef __fp16 h16x4 __attribute__((ext_vector_type(4)));
typedef __fp16 h16x2 __attribute__((ext_vector_type(2)));
typedef int i32x4 __attribute__((ext_vector_type(4)));

__device__ __forceinline__ void gload_lds16(const void* g, void* l) {
  __builtin_amdgcn_global_load_lds(
      (const __attribute__((address_space(1))) unsigned int*)g,
      (__attribute__((address_space(3))) unsigned int*)l, 16, 0, 0);
}

// ---------------- KB: adj int32 -> u16 bitmask, ROW-MAJOR [row][j16] (8 MB).
// Reads: 4KB contiguous per wave. Writes: 128B contiguous per wave.
__global__ __launch_bounds__(256) void kb_pack(const int* __restrict__ adj,
                                               unsigned short* __restrict__ adjb) {
  int gid = blockIdx.x * 256 + threadIdx.x;
#pragma unroll
  for (int it = 0; it < 8; ++it) {
    size_t c = (size_t)it * 524288 + gid;     // u16-chunk index, 4M total
    const int* p = adj + c * 16;
    i32x4 v0 = *(const i32x4*)(p);
    i32x4 v1 = *(const i32x4*)(p + 4);
    i32x4 v2 = *(const i32x4*)(p + 8);
    i32x4 v3 = *(const i32x4*)(p + 12);
    unsigned int b = 0;
#pragma unroll
    for (int k = 0; k < 4; ++k) {
      b |= (v0[k] != 0 ? 1u : 0u) << k;
      b |= (v1[k] != 0 ? 1u : 0u) << (4 + k);
      b |= (v2[k] != 0 ? 1u : 0u) << (8 + k);
      b |= (v3[k] != 0 ? 1u : 0u) << (12 + k);
    }
    adjb[c] = (unsigned short)b;
  }
}

// ---------------- K0: W (256x128 f32) -> WT_perm f16 (for K1's 32x32x16 MFMA)
__global__ __launch_bounds__(256) void k0_wt(const float* __restrict__ W1,
                                             const float* __restrict__ W2,
                                             __fp16* __restrict__ WT) {
  int m = blockIdx.x * 256 + threadIdx.x;  // 8192 chunks of 16B
  int h = m >> 12;
  int r = m & 4095;
  int c = r >> 5;
  int kb = (r >> 1) & 15;
  int hh = r & 1;
  const float* W = h ? W2 : W1;
  float v[8];
#pragma unroll
  for (int s = 0; s < 8; ++s) {
    int koff = 4 * hh + (s & 3) + 8 * (s >> 2);
    v[s] = W[(kb * 16 + koff) * OUTF + c];
  }
  union { h16x2 h2[4]; i32x4 q; } u;
  u.h2[0] = __builtin_amdgcn_cvt_pkrtz(v[0], v[1]);
  u.h2[1] = __builtin_amdgcn_cvt_pkrtz(v[2], v[3]);
  u.h2[2] = __builtin_amdgcn_cvt_pkrtz(v[4], v[5]);
  u.h2[3] = __builtin_amdgcn_cvt_pkrtz(v[6], v[7]);
  *(i32x4*)(WT + (size_t)h * 32768 + c * 256 + kb * 16 + hh * 8) = u.q;
}

// ---------------- K1: h = inp@W via MFMA; emits hT2 in 32x32x16 B-frag layout:
// [head][j16][nf4][lane64][slot8] f16; also src'/dst' scaled by log2e.
__global__ __launch_bounds__(128) void k1_h(
    const float* __restrict__ inp, const __fp16* __restrict__ WT,
    const float* __restrict__ a1, const float* __restrict__ a2,
    __fp16* __restrict__ hT2, float* __restrict__ S, float* __restrict__ D) {
  __shared__ __align__(16) float hl[2][32][136];
  int tid = threadIdx.x;
  int w = tid >> 6;           // wave = head
  int l = tid & 63;
  int lr = l & 31, g = l >> 5;
  int i0 = blockIdx.x * 32;
  const __fp16* WTh = WT + (size_t)w * 32768;
  f32x16 acc[4];
#pragma unroll
  for (int nf = 0; nf < 4; ++nf)
#pragma unroll
    for (int e = 0; e < 16; ++e) acc[nf][e] = 0.0f;
  const float* ip = inp + (size_t)(i0 + lr) * INF;
#pragma unroll
  for (int kb = 0; kb < 16; ++kb) {
    f32x4 q0 = *(const f32x4*)(ip + kb * 16 + 4 * g);
    f32x4 q1 = *(const f32x4*)(ip + kb * 16 + 8 + 4 * g);
    union { h16x2 h2[4]; h16x8 h8; } ua;
    ua.h2[0] = __builtin_amdgcn_cvt_pkrtz(q0[0], q0[1]);
    ua.h2[1] = __builtin_amdgcn_cvt_pkrtz(q0[2], q0[3]);
    ua.h2[2] = __builtin_amdgcn_cvt_pkrtz(q1[0], q1[1]);
    ua.h2[3] = __builtin_amdgcn_cvt_pkrtz(q1[2], q1[3]);
#pragma unroll
    for (int nf = 0; nf < 4; ++nf) {
      h16x8 b = *(const h16x8*)(WTh + (nf * 32 + lr) * 256 + kb * 16 + g * 8);
      acc[nf] = __builtin_amdgcn_mfma_f32_32x32x16_f16(ua.h8, b, acc[nf], 0, 0, 0);
    }
  }
#pragma unroll
  for (int nf = 0; nf < 4; ++nf)
#pragma unroll
    for (int r = 0; r < 16; ++r) {
      int row = (r & 3) + 8 * (r >> 2) + 4 * g;
      hl[w][row][nf * 32 + lr] = acc[nf][r];
    }
  __syncthreads();
  const float* av = w ? a2 : a1;
  float s = 0.f, d = 0.f;
#pragma unroll
  for (int cc = 0; cc < 64; cc += 4) {
    int c = g * 64 + cc;
    f32x4 hv = *(const f32x4*)&hl[w][lr][c];
    f32x4 as = *(const f32x4*)(av + c);
    f32x4 ad = *(const f32x4*)(av + 128 + c);
    s += hv[0] * as[0] + hv[1] * as[1] + hv[2] * as[2] + hv[3] * as[3];
    d += hv[0] * ad[0] + hv[1] * ad[1] + hv[2] * ad[2] + hv[3] * ad[3];
  }
  s += __shfl_xor(s, 32);
  d += __shfl_xor(d, 32);
  if (g == 0) {
    S[(size_t)w * NN + i0 + lr] = s * LOG2E;
    D[(size_t)w * NN + i0 + lr] = d * LOG2E;
  }
  // hT2 emission: per head, 2 j16-blocks x 256 chunks(16B) = 512; 64 lanes x 8 iters.
  __fp16* hTh = hT2 + (size_t)w * (NN * OUTF);
#pragma unroll
  for (int it = 0; it < 8; ++it) {
    int id = it * 64 + l;           // [0,512)
    int jb = id >> 8;
    int sub = id & 255;
    int nf = sub >> 6, lq = sub & 63;
    int lqr = lq & 31, lqg = lq >> 5;
    float v[8];
#pragma unroll
    for (int s2 = 0; s2 < 8; ++s2) {
      int kloc = 4 * lqg + (s2 & 3) + 8 * (s2 >> 2);   // MFMA k-map (A/B identical)
      v[s2] = hl[w][jb * 16 + kloc][nf * 32 + lqr];
    }
    union { h16x2 h2[4]; i32x4 q; } u2;
    u2.h2[0] = __builtin_amdgcn_cvt_pkrtz(v[0], v[1]);
    u2.h2[1] = __builtin_amdgcn_cvt_pkrtz(v[2], v[3]);
    u2.h2[2] = __builtin_amdgcn_cvt_pkrtz(v[4], v[5]);
    u2.h2[3] = __builtin_amdgcn_cvt_pkrtz(v[6], v[7]);
    *(i32x4*)(hTh + (size_t)((i0 >> 4) + jb) * 2048 + sub * 8) = u2.q;
  }
}

// ---------------- K1c: gmax' per head
__global__ __launch_bounds__(256) void k1c_gmax(const float* __restrict__ D,
                                                float* __restrict__ GM) {
  __shared__ float r1[256], r2[256];
  int t = threadIdx.x;
  float m1 = -1e30f, m2 = -1e30f;
  for (int i = t; i < NN; i += 256) {
    m1 = fmaxf(m1, D[i]);
    m2 = fmaxf(m2, D[NN + i]);
  }
  r1[t] = m1; r2[t] = m2;
  __syncthreads();
  for (int s = 128; s > 0; s >>= 1) {
    if (t < s) { r1[t] = fmaxf(r1[t], r1[t + s]); r2[t] = fmaxf(r2[t], r2[t + s]); }
    __syncthreads();
  }
  if (t == 0) { GM[0] = r1[0]; GM[1] = r2[0]; }
}

// ---------------- K2: bitmask softmax + PV, 32x32x16 MFMA, LDS-staged B-frags.
// grid 512 = 64 rowblocks(BM=128) x 8 js; 8 waves = 2 heads x 4 rowgroups(32).
// Row-major mask: one 128B line per (row, js) held in regs, refreshed every 4 jsteps.
__global__ __launch_bounds__(512, 4) void k2_attn(
    const unsigned short* __restrict__ adjb, const __fp16* __restrict__ hT2,
    const float* __restrict__ S, const float* __restrict__ D,
    const float* __restrict__ GM, __fp16* __restrict__ NUM, float* __restrict__ DEN) {
  __shared__ __align__(16) char smem[32768];  // 2 buf x (2 kk x 2 heads x 4KB)
  int tid = threadIdx.x;
  int w = tid >> 6;
  int l = tid & 63;
  int lr = l & 31, g2 = l >> 5;
  int h = w >> 2, rq = w & 3;
  int rb = blockIdx.x >> 3, js = blockIdx.x & 7;
  int i0 = rb * 128;
  int jwin = js * 1024, jw16 = js * 64;
  int row = i0 + rq * 32 + lr;
  float sf = S[(size_t)h * NN + row];
  float gm = GM[h];
  float v0 = sf + gm;
  float cneg = -fmaxf(v0, 0.2f * v0) - 1000.0f;
  const float* Dh = D + (size_t)h * NN + jwin + 4 * g2;

  f32x16 acc[4];
#pragma unroll
  for (int nf = 0; nf < 4; ++nf)
#pragma unroll
    for (int e = 0; e < 16; ++e) acc[nf][e] = 0.0f;
  float dsum = 0.f;

  auto STAGE = [&](int jstep, int b) {
#pragma unroll
    for (int q = 0; q < 2; ++q) {
      int gi = q * 512 + tid;          // 16B-unit id in [0,1024)
      int seg = gi >> 8;               // kk*2 + hh
      int kk_l = seg >> 1, hh = seg & 1;
      const __fp16* gs = hT2 + (size_t)hh * (NN * OUTF) +
                         (size_t)(jw16 + jstep * 2 + kk_l) * 2048 + (gi & 255) * 8;
      char* ld = smem + b * 16384 + gi * 16;  // wave-uniform base + lane*16
      gload_lds16(gs, ld);
    }
  };

  // per-lane mask window: 64 u16 = 128B line; hold 8 u16, refresh every 4 jsteps
  const unsigned short* mrow = adjb + (size_t)row * 512 + jw16;
  i32x4 mreg = *(const i32x4*)(mrow);       // jsteps 0..3
  i32x4 mnext = *(const i32x4*)(mrow + 8);  // jsteps 4..7

  STAGE(0, 0);
  __syncthreads();

  int b = 0;
  for (int jstep = 0; jstep < 32; ++jstep) {
    if (jstep < 31) STAGE(jstep + 1, b ^ 1);
    if ((jstep & 3) == 0 && jstep) {
      mreg = mnext;
      if (jstep < 28) mnext = *(const i32x4*)(mrow + (jstep + 4) * 2);
    }
    unsigned int dw = (unsigned int)mreg[jstep & 3];
    unsigned int bits[2] = {dw & 0xffffu, dw >> 16};
#pragma unroll
    for (int kk = 0; kk < 2; ++kk) {
      int kkg = jstep * 2 + kk;
      f32x4 d0 = *(const f32x4*)(Dh + kkg * 16);
      f32x4 d1 = *(const f32x4*)(Dh + kkg * 16 + 8);
      unsigned int bt = bits[kk];
      float pv[8];
#pragma unroll
      for (int s = 0; s < 8; ++s) {
        float dd = (s < 4) ? d0[s] : d1[s - 4];
        int kloc = 4 * g2 + (s & 3) + 8 * (s >> 2);
        float tt = sf + dd;
        float u = fmaxf(tt, 0.2f * tt) + cneg;
        float bf = (float)((bt >> kloc) & 1u);
        pv[s] = __builtin_amdgcn_exp2f(fmaf(bf, 1000.0f, u));
      }
      dsum += ((pv[0] + pv[1]) + (pv[2] + pv[3])) + ((pv[4] + pv[5]) + (pv[6] + pv[7]));
      union { h16x2 h2[4]; h16x8 h8; } up;
      up.h2[0] = __builtin_amdgcn_cvt_pkrtz(pv[0], pv[1]);
      up.h2[1] = __builtin_amdgcn_cvt_pkrtz(pv[2], pv[3]);
      up.h2[2] = __builtin_amdgcn_cvt_pkrtz(pv[4], pv[5]);
      up.h2[3] = __builtin_amdgcn_cvt_pkrtz(pv[6], pv[7]);
      const char* lb = smem + b * 16384 + (kk * 2 + h) * 4096 + l * 16;
#pragma unroll
      for (int nf = 0; nf < 4; ++nf) {
        h16x8 Bf = *(const h16x8*)(lb + nf * 1024);
        acc[nf] = __builtin_amdgcn_mfma_f32_32x32x16_f16(up.h8, Bf, acc[nf], 0, 0, 0);
      }
    }
    __syncthreads();
    b ^= 1;
  }

  // denom: lanes l and l+32 share a row
  dsum += __shfl_xor(dsum, 32);
  if (g2 == 0) DEN[(size_t)(js * 2 + h) * NN + row] = dsum;
  // C layout (32x32): col = lr, crow = (r&3)+8*(r>>2)+4*g2
  __fp16* nb = NUM + ((size_t)(js * 2 + h) * NN + i0 + rq * 32) * 128 + lr;
#pragma unroll
  for (int nf = 0; nf < 4; ++nf)
#pragma unroll
    for (int r = 0; r < 16; ++r) {
      int crow = (r & 3) + 8 * (r >> 2) + 4 * g2;
      nb[(size_t)crow * 128 + nf * 32] = (__fp16)acc[nf][r];
    }
}

// ---------------- K3: merge js partials, combine heads, ELU
__global__ __launch_bounds__(256) void k3_out(const __fp16* __restrict__ NUM,
                                              const float* __restrict__ DEN,
                                              float* __restrict__ out) {
  int gid = blockIdx.x * 256 + threadIdx.x;  // 262144
  int i = gid >> 5;
  int c4 = (gid & 31) * 4;
  f32x4 n1 = {0.f, 0.f, 0.f, 0.f}, n2 = {0.f, 0.f, 0.f, 0.f};
  float d1 = 0.f, d2 = 0.f;
#pragma unroll
  for (int js = 0; js < 8; ++js) {
    h16x4 a1v = *(const h16x4*)(NUM + ((size_t)(js * 2 + 0) * NN + i) * 128 + c4);
    h16x4 a2v = *(const h16x4*)(NUM + ((size_t)(js * 2 + 1) * NN + i) * 128 + c4);
#pragma unroll
    for (int e = 0; e < 4; ++e) { n1[e] += (float)a1v[e]; n2[e] += (float)a2v[e]; }
    d1 += DEN[(size_t)(js * 2 + 0) * NN + i];
    d2 += DEN[(size_t)(js * 2 + 1) * NN + i];
  }
  float r1 = 1.0f / d1, r2 = 0.5f / d2;
  f32x4 o;
#pragma unroll
  for (int e = 0; e < 4; ++e) {
    float x = n1[e] * r1 + n2[e] * r2;
    o[e] = x > 0.f ? x : (exp2f(x * LOG2E) - 1.0f);
  }
  *(f32x4*)(out + (size_t)i * 128 + c4) = o;
}

extern "C" void kernel_launch(void* const* d_in, const int* in_sizes, int n_in,
                              void* d_out, int out_size, void* d_ws, size_t ws_size,
                              hipStream_t stream) {
  const float* inp = (const float*)d_in[0];
  const int* adj = (const int*)d_in[1];
  const float* W1 = (const float*)d_in[2];
  const float* a1 = (const float*)d_in[3];
  const float* W2 = (const float*)d_in[4];
  const float* a2 = (const float*)d_in[5];
  float* out = (float*)d_out;
  char* ws = (char*)d_ws;
  // ws layout (~46.9 MB):
  __fp16* WT = (__fp16*)(ws);                              // 128 KB
  __fp16* hT2 = (__fp16*)(ws + 131072);                    // 4 MB
  float* S = (float*)(ws + 4325376);                       // 64 KB
  float* D = (float*)(ws + 4390912);                       // 64 KB
  float* GM = (float*)(ws + 4456448);                      // 256 B
  unsigned short* adjb = (unsigned short*)(ws + 4456704);  // 8 MB row-major
  __fp16* NUM = (__fp16*)(ws + 12845312);                  // 32 MB
  float* DEN = (float*)(ws + 46399744);                    // 512 KB

  kb_pack<<<dim3(2048), dim3(256), 0, stream>>>(adj, adjb);
  k0_wt<<<dim3(32), dim3(256), 0, stream>>>(W1, W2, WT);
  k1_h<<<dim3(256), dim3(128), 0, stream>>>(inp, WT, a1, a2, hT2, S, D);
  k1c_gmax<<<dim3(1), dim3(256), 0, stream>>>(D, GM);
  k2_attn<<<dim3(512), dim3(512), 0, stream>>>(adjb, hT2, S, D, GM, NUM, DEN);
  k3_out<<<dim3(1024), dim3(256), 0, stream>>>(NUM, DEN, out);
}